// Round 13
// baseline (299.304 us; speedup 1.0000x reference)
//
#include <hip/hip_runtime.h>
#include <hip/hip_fp16.h>

#define N_IN   20000
#define N_OUT  20000
#define NEDGE  640000
#define B      64
#define NB     625      // buckets: dst>>5, 32 dsts each (625*32 = 20000 exactly)
#define BCAP   1280     // slots/bucket; Binomial mean 1024, sigma 32 -> 8-sigma margin
#define CHUNK  8192     // edges per partition block
#define PBLK   ((NEDGE + CHUNK - 1) / CHUNK)   // 79

// prep: xt[i*B+b] = (half)(alpha[i]*x[b*N_IN+i]); pack psrc4/pdst4; zero gcur
__global__ void prep_kernel(const float* __restrict__ x,
                            const float* __restrict__ alpha,
                            const float* __restrict__ ipos,
                            const float* __restrict__ opos,
                            const float* __restrict__ sigma,
                            __half* __restrict__ xt,
                            float4* __restrict__ psrc4,
                            float4* __restrict__ pdst4,
                            int* __restrict__ gcur) {
    const int g = blockIdx.x * 256 + threadIdx.x;
    if (g < N_IN)
        psrc4[g] = make_float4(ipos[3 * g], ipos[3 * g + 1], ipos[3 * g + 2], sigma[g]);
    if (g < N_OUT)
        pdst4[g] = make_float4(opos[3 * g], opos[3 * g + 1], opos[3 * g + 2], 0.0f);
    if (g < NB) gcur[g] = 0;

    __shared__ float tile[64][65];
    const int i0 = blockIdx.x * 64;
    const int tx = threadIdx.x & 63;
    const int ty = threadIdx.x >> 6;
    const int i  = i0 + tx;
    const float a = (i < N_IN) ? alpha[i] : 0.0f;
    #pragma unroll
    for (int k = 0; k < 16; ++k) {
        const int b = ty + (k << 2);
        tile[b][tx] = (i < N_IN) ? a * x[(size_t)b * N_IN + i] : 0.0f;
    }
    __syncthreads();
    #pragma unroll
    for (int k = 0; k < 16; ++k) {
        const int ii = ty + (k << 2);
        const int gi = i0 + ii;
        if (gi < N_IN) xt[(size_t)gi * B + tx] = __float2half(tile[tx][ii]);
    }
}

// partition: LDS-aggregated bucket binning. Per block: stage CHUNK edges,
// LDS-count per bucket, ONE global atomic per (block,bucket), then write
// packed (dst<<16|src) into bucket runs (same-bucket entries contiguous).
__global__ __launch_bounds__(256)
void partition_kernel(const int* __restrict__ edge,
                      int* __restrict__ gcur,
                      unsigned int* __restrict__ gbuf) {
    __shared__ unsigned int ebuf[CHUNK];
    __shared__ int count[NB];
    __shared__ int cnt2[NB];
    __shared__ int gbase[NB];
    const int t = threadIdx.x;
    const int e_base = blockIdx.x * CHUNK;
    const int ne = min(CHUNK, NEDGE - e_base);

    for (int b = t; b < NB; b += 256) { count[b] = 0; cnt2[b] = 0; }
    __syncthreads();

    // stage + count (int4 loads: 4 edges per round per thread)
    #pragma unroll
    for (int k = 0; k < CHUNK / 4 / 256; ++k) {
        const int i4 = (t + 256 * k) * 4;
        if (i4 < ne) {
            const int4 d4 = *reinterpret_cast<const int4*>(edge + e_base + i4);
            const int4 s4 = *reinterpret_cast<const int4*>(edge + NEDGE + e_base + i4);
            ebuf[i4 + 0] = ((unsigned int)d4.x << 16) | (unsigned int)s4.x;
            ebuf[i4 + 1] = ((unsigned int)d4.y << 16) | (unsigned int)s4.y;
            ebuf[i4 + 2] = ((unsigned int)d4.z << 16) | (unsigned int)s4.z;
            ebuf[i4 + 3] = ((unsigned int)d4.w << 16) | (unsigned int)s4.w;
            atomicAdd(&count[d4.x >> 5], 1);
            atomicAdd(&count[d4.y >> 5], 1);
            atomicAdd(&count[d4.z >> 5], 1);
            atomicAdd(&count[d4.w >> 5], 1);
        }
    }
    __syncthreads();

    // one global atomic per non-empty bucket
    for (int b = t; b < NB; b += 256)
        if (count[b]) gbase[b] = atomicAdd(&gcur[b], count[b]);
    __syncthreads();

    // write out: slot = gbase + local rank (same-bucket entries contiguous)
    #pragma unroll
    for (int k = 0; k < CHUNK / 256; ++k) {
        const int i = t + 256 * k;
        if (i < ne) {
            const unsigned int u = ebuf[i];
            const int b = u >> 21;                      // dst>>5
            const int pos = gbase[b] + atomicAdd(&cnt2[b], 1);
            if (pos < BCAP) gbuf[(size_t)b * BCAP + pos] = u;
        }
    }
}

// bucket_gather: one block per bucket (32 dsts). Phase A: stage edges +
// exact f32 w in LDS. Phase B: 8 waves stream edges (8-deep xt MLP),
// lane = batch, ds_add_f32 accumulate into acc[dst_local][batch].
__global__ __launch_bounds__(512, 2)
void bucket_gather_kernel(const int* __restrict__ gcur,
                          const unsigned int* __restrict__ gbuf,
                          const float4* __restrict__ psrc4,
                          const float4* __restrict__ pdst4,
                          const __half* __restrict__ xt,
                          float* __restrict__ y) {
    __shared__ float        acc[32][65];
    __shared__ float        wbuf[BCAP];
    __shared__ unsigned int sb[BCAP];
    __shared__ float4       pd[32];
    const int t  = threadIdx.x;
    const int g  = blockIdx.x;
    const int ne = min(gcur[g], BCAP);

    for (int i = t; i < 32 * 65; i += 512) (&acc[0][0])[i] = 0.0f;
    if (t < 32) pd[t] = pdst4[g * 32 + t];
    __syncthreads();

    // phase A: per-edge exact w
    for (int i = t; i < ne; i += 512) {
        const unsigned int u = gbuf[(size_t)g * BCAP + i];
        const int src = u & 0xffffu;
        const int dl  = (u >> 16) & 31;
        const float4 ps = psrc4[src];
        const float dx = ps.x - pd[dl].x;
        const float dy = ps.y - pd[dl].y;
        const float dz = ps.z - pd[dl].z;
        wbuf[i] = __expf(-(dx * dx + dy * dy + dz * dz) / (ps.w * ps.w));
        sb[i] = u;
    }
    __syncthreads();

    // phase B: 8 waves, 8 edges per round per wave
    const int lane = t & 63;
    const int wv   = t >> 6;   // 0..7
    for (int i0 = wv * 8; i0 < ne; i0 += 64) {
        int   s_[8], dl_[8];
        float w_[8], v_[8];
        #pragma unroll
        for (int j = 0; j < 8; ++j) {
            const int i = i0 + j;
            const bool ok = i < ne;
            const unsigned int u = ok ? sb[i] : 0u;
            s_[j]  = u & 0xffffu;
            dl_[j] = (u >> 16) & 31;
            w_[j]  = ok ? wbuf[i] : 0.0f;
        }
        #pragma unroll
        for (int j = 0; j < 8; ++j)
            v_[j] = __half2float(xt[(size_t)s_[j] * B + lane]);
        #pragma unroll
        for (int j = 0; j < 8; ++j)
            atomicAdd(&acc[dl_[j]][lane], w_[j] * v_[j]);
    }
    __syncthreads();

    // write-out: y[b][g*32 + j], 128B coalesced runs
    const int j  = t & 31;
    const int b0 = t >> 5;   // 0..15
    #pragma unroll
    for (int p = 0; p < 4; ++p) {
        const int b = b0 * 4 + p;
        y[(size_t)b * N_OUT + g * 32 + j] = acc[j][b];
    }
}

extern "C" void kernel_launch(void* const* d_in, const int* in_sizes, int n_in,
                              void* d_out, int out_size, void* d_ws, size_t ws_size,
                              hipStream_t stream) {
    const float* x     = (const float*)d_in[0];
    const float* alpha = (const float*)d_in[1];
    const float* sigma = (const float*)d_in[2];
    const float* ipos  = (const float*)d_in[3];
    const float* opos  = (const float*)d_in[4];
    const int*   edge  = (const int*)d_in[5];
    float* y = (float*)d_out;

    __half*       xt    = (__half*)d_ws;                             // 2.56 MB
    unsigned int* gbuf  = (unsigned int*)(xt + (size_t)N_IN * B);    // 3.20 MB
    float4*       psrc4 = (float4*)(gbuf + (size_t)NB * BCAP);       // 320 KB
    float4*       pdst4 = psrc4 + N_IN;                              // 320 KB
    int*          gcur  = (int*)(pdst4 + N_OUT);                     // 2.5 KB

    prep_kernel<<<313, 256, 0, stream>>>(x, alpha, ipos, opos, sigma,
                                         xt, psrc4, pdst4, gcur);
    partition_kernel<<<PBLK, 256, 0, stream>>>(edge, gcur, gbuf);
    bucket_gather_kernel<<<NB, 512, 0, stream>>>(gcur, gbuf, psrc4, pdst4, xt, y);
}

// Round 14
// 48.376 us; speedup vs baseline: 6.1871x; 6.1871x over previous
//
#include <hip/hip_runtime.h>
#include <hip/hip_fp16.h>

#define N_IN   20000
#define N_OUT  20000
#define NEDGE  640000
#define B      64
#define NB     625      // buckets: dst>>5, 32 dsts each (625*32 = 20000 exactly)
#define BCAP   1280     // slots/bucket; Binomial mean 1024, sigma 32 -> 8-sigma margin
#define CHUNK  8192     // edges per partition block
#define PBLK   ((NEDGE + CHUNK - 1) / CHUNK)   // 79

// prep: xt[i*B+b] = (half)(alpha[i]*x[b*N_IN+i]); pack psrc4/pdst4; zero gcur
__global__ void prep_kernel(const float* __restrict__ x,
                            const float* __restrict__ alpha,
                            const float* __restrict__ ipos,
                            const float* __restrict__ opos,
                            const float* __restrict__ sigma,
                            __half* __restrict__ xt,
                            float4* __restrict__ psrc4,
                            float4* __restrict__ pdst4,
                            int* __restrict__ gcur) {
    const int g = blockIdx.x * 256 + threadIdx.x;
    if (g < N_IN)
        psrc4[g] = make_float4(ipos[3 * g], ipos[3 * g + 1], ipos[3 * g + 2], sigma[g]);
    if (g < N_OUT)
        pdst4[g] = make_float4(opos[3 * g], opos[3 * g + 1], opos[3 * g + 2], 0.0f);
    if (g < NB) gcur[g] = 0;

    __shared__ float tile[64][65];
    const int i0 = blockIdx.x * 64;
    const int tx = threadIdx.x & 63;
    const int ty = threadIdx.x >> 6;
    const int i  = i0 + tx;
    const float a = (i < N_IN) ? alpha[i] : 0.0f;
    #pragma unroll
    for (int k = 0; k < 16; ++k) {
        const int b = ty + (k << 2);
        tile[b][tx] = (i < N_IN) ? a * x[(size_t)b * N_IN + i] : 0.0f;
    }
    __syncthreads();
    #pragma unroll
    for (int k = 0; k < 16; ++k) {
        const int ii = ty + (k << 2);
        const int gi = i0 + ii;
        if (gi < N_IN) xt[(size_t)gi * B + tx] = __float2half(tile[tx][ii]);
    }
}

// partition: LDS-aggregated bucket binning (proven ~8us in R13). Per block:
// stage CHUNK edges, LDS-count per bucket, ONE global atomic per
// (block,bucket), write packed (dst<<16|src) into contiguous bucket runs.
__global__ __launch_bounds__(256)
void partition_kernel(const int* __restrict__ edge,
                      int* __restrict__ gcur,
                      unsigned int* __restrict__ gbuf) {
    __shared__ unsigned int ebuf[CHUNK];
    __shared__ int count[NB];
    __shared__ int cnt2[NB];
    __shared__ int gbase[NB];
    const int t = threadIdx.x;
    const int e_base = blockIdx.x * CHUNK;
    const int ne = min(CHUNK, NEDGE - e_base);

    for (int b = t; b < NB; b += 256) { count[b] = 0; cnt2[b] = 0; }
    __syncthreads();

    #pragma unroll
    for (int k = 0; k < CHUNK / 4 / 256; ++k) {
        const int i4 = (t + 256 * k) * 4;
        if (i4 < ne) {
            const int4 d4 = *reinterpret_cast<const int4*>(edge + e_base + i4);
            const int4 s4 = *reinterpret_cast<const int4*>(edge + NEDGE + e_base + i4);
            ebuf[i4 + 0] = ((unsigned int)d4.x << 16) | (unsigned int)s4.x;
            ebuf[i4 + 1] = ((unsigned int)d4.y << 16) | (unsigned int)s4.y;
            ebuf[i4 + 2] = ((unsigned int)d4.z << 16) | (unsigned int)s4.z;
            ebuf[i4 + 3] = ((unsigned int)d4.w << 16) | (unsigned int)s4.w;
            atomicAdd(&count[d4.x >> 5], 1);
            atomicAdd(&count[d4.y >> 5], 1);
            atomicAdd(&count[d4.z >> 5], 1);
            atomicAdd(&count[d4.w >> 5], 1);
        }
    }
    __syncthreads();

    for (int b = t; b < NB; b += 256)
        if (count[b]) gbase[b] = atomicAdd(&gcur[b], count[b]);
    __syncthreads();

    #pragma unroll
    for (int k = 0; k < CHUNK / 256; ++k) {
        const int i = t + 256 * k;
        if (i < ne) {
            const unsigned int u = ebuf[i];
            const int b = u >> 21;                      // dst>>5
            const int pos = gbase[b] + atomicAdd(&cnt2[b], 1);
            if (pos < BCAP) gbuf[(size_t)b * BCAP + pos] = u;
        }
    }
}

// bucket_gather v2: one block per bucket (32 dsts, 8 waves).
// Pass 1: count 32 dst-local bins. Scan. Pass 2: compute exact f32 w once
// per edge, place (src,w) SORTED by dst_local in LDS (no acc atomics).
// Phase B: wave wv owns dsts 4wv..4wv+3, register accumulation with
// 8-deep xt MLP (the proven R12 inner loop). Coalesced y write-out.
__global__ __launch_bounds__(512, 2)
void bucket_gather_kernel(const int* __restrict__ gcur,
                          const unsigned int* __restrict__ gbuf,
                          const float4* __restrict__ psrc4,
                          const float4* __restrict__ pdst4,
                          const __half* __restrict__ xt,
                          float* __restrict__ y) {
    __shared__ float          sw[BCAP];
    __shared__ unsigned short ss[BCAP];
    __shared__ int            bins[32];
    __shared__ int            cnt2[32];
    __shared__ int            base[33];
    __shared__ float4         pd[32];
    __shared__ float          tile[32][65];
    const int t  = threadIdx.x;
    const int g  = blockIdx.x;
    const int ne = min(gcur[g], BCAP);

    if (t < 32) { bins[t] = 0; cnt2[t] = 0; pd[t] = pdst4[g * 32 + t]; }
    __syncthreads();

    // pass 1: count dst-local bins
    for (int i = t; i < ne; i += 512)
        atomicAdd(&bins[(gbuf[(size_t)g * BCAP + i] >> 16) & 31], 1);
    __syncthreads();

    if (t == 0) {
        int s = 0;
        #pragma unroll
        for (int j = 0; j < 32; ++j) { base[j] = s; s += bins[j]; }
        base[32] = s;
    }
    __syncthreads();

    // pass 2: exact w once per edge, sorted placement
    for (int i = t; i < ne; i += 512) {
        const unsigned int u = gbuf[(size_t)g * BCAP + i];
        const int src = u & 0xffffu;
        const int dl  = (u >> 16) & 31;
        const float4 ps = psrc4[src];
        const float dx = ps.x - pd[dl].x;
        const float dy = ps.y - pd[dl].y;
        const float dz = ps.z - pd[dl].z;
        const float w  = __expf(-(dx * dx + dy * dy + dz * dz) / (ps.w * ps.w));
        const int r = base[dl] + atomicAdd(&cnt2[dl], 1);
        sw[r] = w;
        ss[r] = (unsigned short)src;
    }
    __syncthreads();

    // phase B: register accumulation, 8 gathers in flight
    const int lane = t & 63;
    const int wv   = t >> 6;   // 0..7
    #pragma unroll
    for (int q = 0; q < 4; ++q) {
        const int dl = wv * 4 + q;
        int k = base[dl];
        const int end = base[dl + 1];
        float acc0 = 0.0f, acc1 = 0.0f;
        for (; k + 8 <= end; k += 8) {
            const int   s0 = ss[k],     s1 = ss[k + 1];
            const int   s2 = ss[k + 2], s3 = ss[k + 3];
            const int   s4 = ss[k + 4], s5 = ss[k + 5];
            const int   s6 = ss[k + 6], s7 = ss[k + 7];
            const float w0 = sw[k],     w1 = sw[k + 1];
            const float w2 = sw[k + 2], w3 = sw[k + 3];
            const float w4 = sw[k + 4], w5 = sw[k + 5];
            const float w6 = sw[k + 6], w7 = sw[k + 7];
            const float v0 = __half2float(xt[(size_t)s0 * B + lane]);
            const float v1 = __half2float(xt[(size_t)s1 * B + lane]);
            const float v2 = __half2float(xt[(size_t)s2 * B + lane]);
            const float v3 = __half2float(xt[(size_t)s3 * B + lane]);
            const float v4 = __half2float(xt[(size_t)s4 * B + lane]);
            const float v5 = __half2float(xt[(size_t)s5 * B + lane]);
            const float v6 = __half2float(xt[(size_t)s6 * B + lane]);
            const float v7 = __half2float(xt[(size_t)s7 * B + lane]);
            acc0 = fmaf(w0, v0, acc0);
            acc1 = fmaf(w1, v1, acc1);
            acc0 = fmaf(w2, v2, acc0);
            acc1 = fmaf(w3, v3, acc1);
            acc0 = fmaf(w4, v4, acc0);
            acc1 = fmaf(w5, v5, acc1);
            acc0 = fmaf(w6, v6, acc0);
            acc1 = fmaf(w7, v7, acc1);
        }
        for (; k < end; ++k)
            acc0 = fmaf(sw[k], __half2float(xt[(size_t)ss[k] * B + lane]), acc0);
        tile[dl][lane] = acc0 + acc1;
    }
    __syncthreads();

    // write-out: y[b][g*32 + j] in 128B coalesced runs
    const int j  = t & 31;
    const int b0 = t >> 5;   // 0..15
    #pragma unroll
    for (int p = 0; p < 4; ++p) {
        const int b = b0 * 4 + p;
        y[(size_t)b * N_OUT + g * 32 + j] = tile[j][b];
    }
}

extern "C" void kernel_launch(void* const* d_in, const int* in_sizes, int n_in,
                              void* d_out, int out_size, void* d_ws, size_t ws_size,
                              hipStream_t stream) {
    const float* x     = (const float*)d_in[0];
    const float* alpha = (const float*)d_in[1];
    const float* sigma = (const float*)d_in[2];
    const float* ipos  = (const float*)d_in[3];
    const float* opos  = (const float*)d_in[4];
    const int*   edge  = (const int*)d_in[5];
    float* y = (float*)d_out;

    __half*       xt    = (__half*)d_ws;                             // 2.56 MB
    unsigned int* gbuf  = (unsigned int*)(xt + (size_t)N_IN * B);    // 3.20 MB
    float4*       psrc4 = (float4*)(gbuf + (size_t)NB * BCAP);       // 320 KB
    float4*       pdst4 = psrc4 + N_IN;                              // 320 KB
    int*          gcur  = (int*)(pdst4 + N_OUT);                     // 2.5 KB

    prep_kernel<<<313, 256, 0, stream>>>(x, alpha, ipos, opos, sigma,
                                         xt, psrc4, pdst4, gcur);
    partition_kernel<<<PBLK, 256, 0, stream>>>(edge, gcur, gbuf);
    bucket_gather_kernel<<<NB, 512, 0, stream>>>(gcur, gbuf, psrc4, pdst4, xt, y);
}

// Round 16
// 41.082 us; speedup vs baseline: 7.2855x; 1.1775x over previous
//
#include <hip/hip_runtime.h>
#include <hip/hip_fp16.h>

#define N_IN   20000
#define N_OUT  20000
#define NEDGE  640000
#define B      64
#define NB     1250     // buckets: dst>>4, 16 dsts each (1250*16 = 20000 exactly)
#define CAPB   32       // slots per (bucket, partition-block); Poisson(6.6) -> +10 sigma
#define BTOT   768      // max edges per bucket in gather LDS; Poisson(512) -> +11 sigma
#define CHUNK  8192     // edges per partition block
#define PBLK   79       // ceil(NEDGE / CHUNK)

// Kernel 1: block-split fusion of partition (blocks 0..78) and prep (79..391).
// Partition uses deterministic per-(bucket,block) regions -> NO global atomics,
// NO pre-zeroed cursors (cnt2d rows are fully written by their owner block).
__global__ __launch_bounds__(256)
void prep_partition_kernel(const int* __restrict__ edge,
                           unsigned int* __restrict__ gbuf,
                           int* __restrict__ cnt2d,
                           const float* __restrict__ x,
                           const float* __restrict__ alpha,
                           const float* __restrict__ ipos,
                           const float* __restrict__ opos,
                           const float* __restrict__ sigma,
                           __half* __restrict__ xt,
                           float4* __restrict__ psrc4,
                           float4* __restrict__ pdst4) {
    const int t = threadIdx.x;
    if (blockIdx.x < PBLK) {
        // ---- partition: bin 8192 edges into 1250 buckets (LDS counters) ----
        __shared__ int cnt[NB];
        const int blk = blockIdx.x;
        const int e_base = blk * CHUNK;
        const int ne = min(CHUNK, NEDGE - e_base);
        for (int b = t; b < NB; b += 256) cnt[b] = 0;
        __syncthreads();
        #pragma unroll
        for (int k = 0; k < CHUNK / 4 / 256; ++k) {
            const int i4 = (t + 256 * k) * 4;
            if (i4 < ne) {
                const int4 d4 = *reinterpret_cast<const int4*>(edge + e_base + i4);
                const int4 s4 = *reinterpret_cast<const int4*>(edge + NEDGE + e_base + i4);
                const int ds[4] = {d4.x, d4.y, d4.z, d4.w};
                const int sr[4] = {s4.x, s4.y, s4.z, s4.w};
                #pragma unroll
                for (int j = 0; j < 4; ++j) {
                    const int bk = ds[j] >> 4;
                    const int slot = atomicAdd(&cnt[bk], 1);
                    if (slot < CAPB)
                        gbuf[((size_t)bk * PBLK + blk) * CAPB + slot] =
                            ((unsigned int)ds[j] << 16) | (unsigned int)sr[j];
                }
            }
        }
        __syncthreads();
        for (int b = t; b < NB; b += 256)
            cnt2d[blk * NB + b] = cnt[b];
    } else {
        // ---- prep: xt transpose + psrc4/pdst4 packing ----
        const int pb = blockIdx.x - PBLK;       // 0..312
        const int g = pb * 256 + t;
        if (g < N_IN)
            psrc4[g] = make_float4(ipos[3 * g], ipos[3 * g + 1], ipos[3 * g + 2], sigma[g]);
        if (g < N_OUT)
            pdst4[g] = make_float4(opos[3 * g], opos[3 * g + 1], opos[3 * g + 2], 0.0f);

        __shared__ float tile[64][65];
        const int i0 = pb * 64;
        const int tx = t & 63;
        const int ty = t >> 6;
        const int i  = i0 + tx;
        const float a = (i < N_IN) ? alpha[i] : 0.0f;
        #pragma unroll
        for (int k = 0; k < 16; ++k) {
            const int b = ty + (k << 2);
            tile[b][tx] = (i < N_IN) ? a * x[(size_t)b * N_IN + i] : 0.0f;
        }
        __syncthreads();
        #pragma unroll
        for (int k = 0; k < 16; ++k) {
            const int ii = ty + (k << 2);
            const int gi = i0 + ii;
            if (gi < N_IN) xt[(size_t)gi * B + tx] = __float2half(tile[tx][ii]);
        }
    }
}

// Kernel 2: one block per bucket (16 dsts, 4 waves, 256 threads).
// Step 1: gather run counts (79 regions), serial scan. Step 2: copy runs into
// LDS + bin-count by dst_local. Step 3: 16-bin scan. Step 4: exact f32 w once
// per edge, sorted placement. Step 5: per-wave register gather (8-deep MLP).
__global__ __launch_bounds__(256, 4)
void bucket_gather_kernel(const int* __restrict__ cnt2d,
                          const unsigned int* __restrict__ gbuf,
                          const float4* __restrict__ psrc4,
                          const float4* __restrict__ pdst4,
                          const __half* __restrict__ xt,
                          float* __restrict__ y) {
    __shared__ unsigned int   ebuf[BTOT];
    __shared__ float          sw[BTOT];
    __shared__ unsigned short ss[BTOT];
    __shared__ int            rcnt[PBLK];
    __shared__ int            rbase[PBLK + 1];
    __shared__ int            bins[16], bcnt[16], base[17];
    __shared__ float4         pd[16];
    __shared__ float          tile[16][65];
    const int t = threadIdx.x;
    const int g = blockIdx.x;

    if (t < 16) { bins[t] = 0; bcnt[t] = 0; pd[t] = pdst4[g * 16 + t]; }
    if (t < PBLK) rcnt[t] = min(cnt2d[t * NB + g], CAPB);
    __syncthreads();
    if (t == 0) {
        int s = 0;
        for (int r = 0; r < PBLK; ++r) { rbase[r] = s; s += rcnt[r]; }
        rbase[PBLK] = s;
    }
    __syncthreads();
    const int ne = min(rbase[PBLK], BTOT);

    // step 2: copy 79 runs into contiguous LDS, count dst-local bins
    for (int idx = t; idx < PBLK * CAPB; idx += 256) {
        const int r = idx >> 5;           // CAPB = 32
        const int s = idx & (CAPB - 1);
        if (s < rcnt[r]) {
            const int pos = rbase[r] + s;
            if (pos < BTOT) {
                const unsigned int u = gbuf[((size_t)g * PBLK + r) * CAPB + s];
                ebuf[pos] = u;
                atomicAdd(&bins[(u >> 16) & 15], 1);
            }
        }
    }
    __syncthreads();
    if (t == 0) {
        int s = 0;
        #pragma unroll
        for (int j = 0; j < 16; ++j) { base[j] = s; s += bins[j]; }
        base[16] = s;
    }
    __syncthreads();

    // step 4: exact w once per edge, sorted placement by dst_local
    for (int i = t; i < ne; i += 256) {
        const unsigned int u = ebuf[i];
        const int src = u & 0xffffu;
        const int dl  = (u >> 16) & 15;
        const float4 ps = psrc4[src];
        const float dx = ps.x - pd[dl].x;
        const float dy = ps.y - pd[dl].y;
        const float dz = ps.z - pd[dl].z;
        const float w  = __expf(-(dx * dx + dy * dy + dz * dz) / (ps.w * ps.w));
        const int r = base[dl] + atomicAdd(&bcnt[dl], 1);
        sw[r] = w;
        ss[r] = (unsigned short)src;
    }
    __syncthreads();

    // step 5: register accumulation, 8 xt gathers in flight; wave wv owns
    // dst-locals 4wv..4wv+3
    const int lane = t & 63;
    const int wv   = t >> 6;   // 0..3
    #pragma unroll
    for (int q = 0; q < 4; ++q) {
        const int dl = wv * 4 + q;
        int k = base[dl];
        const int end = base[dl + 1];
        float acc0 = 0.0f, acc1 = 0.0f;
        for (; k + 8 <= end; k += 8) {
            const int   s0 = ss[k],     s1 = ss[k + 1];
            const int   s2 = ss[k + 2], s3 = ss[k + 3];
            const int   s4 = ss[k + 4], s5 = ss[k + 5];
            const int   s6 = ss[k + 6], s7 = ss[k + 7];
            const float w0 = sw[k],     w1 = sw[k + 1];
            const float w2 = sw[k + 2], w3 = sw[k + 3];
            const float w4 = sw[k + 4], w5 = sw[k + 5];
            const float w6 = sw[k + 6], w7 = sw[k + 7];
            const float v0 = __half2float(xt[(size_t)s0 * B + lane]);
            const float v1 = __half2float(xt[(size_t)s1 * B + lane]);
            const float v2 = __half2float(xt[(size_t)s2 * B + lane]);
            const float v3 = __half2float(xt[(size_t)s3 * B + lane]);
            const float v4 = __half2float(xt[(size_t)s4 * B + lane]);
            const float v5 = __half2float(xt[(size_t)s5 * B + lane]);
            const float v6 = __half2float(xt[(size_t)s6 * B + lane]);
            const float v7 = __half2float(xt[(size_t)s7 * B + lane]);
            acc0 = fmaf(w0, v0, acc0);
            acc1 = fmaf(w1, v1, acc1);
            acc0 = fmaf(w2, v2, acc0);
            acc1 = fmaf(w3, v3, acc1);
            acc0 = fmaf(w4, v4, acc0);
            acc1 = fmaf(w5, v5, acc1);
            acc0 = fmaf(w6, v6, acc0);
            acc1 = fmaf(w7, v7, acc1);
        }
        for (; k < end; ++k)
            acc0 = fmaf(sw[k], __half2float(xt[(size_t)ss[k] * B + lane]), acc0);
        tile[dl][lane] = acc0 + acc1;
    }
    __syncthreads();

    // y write: j = dst-in-bucket (0..15); each thread covers 4 batches
    // b = (t>>4)*4 + p so all 64 batches are written (R15 bug: b = t>>4).
    const int j  = t & 15;
    const int b0 = t >> 4;   // 0..15
    #pragma unroll
    for (int p = 0; p < 4; ++p) {
        const int b = b0 * 4 + p;
        y[(size_t)b * N_OUT + g * 16 + j] = tile[j][b];
    }
}

extern "C" void kernel_launch(void* const* d_in, const int* in_sizes, int n_in,
                              void* d_out, int out_size, void* d_ws, size_t ws_size,
                              hipStream_t stream) {
    const float* x     = (const float*)d_in[0];
    const float* alpha = (const float*)d_in[1];
    const float* sigma = (const float*)d_in[2];
    const float* ipos  = (const float*)d_in[3];
    const float* opos  = (const float*)d_in[4];
    const int*   edge  = (const int*)d_in[5];
    float* y = (float*)d_out;

    __half*       xt    = (__half*)d_ws;                              // 2.56 MB
    unsigned int* gbuf  = (unsigned int*)(xt + (size_t)N_IN * B);     // 12.64 MB
    float4*       psrc4 = (float4*)(gbuf + (size_t)NB * PBLK * CAPB); // 320 KB
    float4*       pdst4 = psrc4 + N_IN;                               // 320 KB
    int*          cnt2d = (int*)(pdst4 + N_OUT);                      // 395 KB

    prep_partition_kernel<<<PBLK + 313, 256, 0, stream>>>(
        edge, gbuf, cnt2d, x, alpha, ipos, opos, sigma, xt, psrc4, pdst4);
    bucket_gather_kernel<<<NB, 256, 0, stream>>>(
        cnt2d, gbuf, psrc4, pdst4, xt, y);
}